// Round 5
// baseline (182.728 us; speedup 1.0000x reference)
//
#include <hip/hip_runtime.h>

#define B_   1024
#define G_   512
#define K_   128
#define J_   129
#define E2_  128
#define KK_  16512      /* K_*J_ */
#define KKE_ 16640      /* KK_ + K_ (appended wimg columns) */
#define KKP_ 16896      /* padded: SPLITS*KCHUNK */
#define SPLITS 16
#define KCHUNK 1056     /* KKP_/SPLITS */
#define BK_  32
#define KSTEPS 33       /* KCHUNK/BK_ */
#define GS_  8          /* g-splits for table partials */

using short8 = __attribute__((ext_vector_type(8))) short;
using f32x4  = __attribute__((ext_vector_type(4))) float;

__device__ __forceinline__ float bf2f(unsigned short h){
  return __uint_as_float(((unsigned int)h) << 16);
}
__device__ __forceinline__ unsigned short f2bf(float f){
  unsigned int u = __float_as_uint(f);
  u += 0x7fffu + ((u >> 16) & 1u);          // round-to-nearest-even
  return (unsigned short)(u >> 16);
}

// ---- block (256-thread, 4-wave) reductions -------------------------------
__device__ __forceinline__ float blockSum256(float v, float* red, int t){
  #pragma unroll
  for (int off = 32; off > 0; off >>= 1) v += __shfl_down(v, off);
  __syncthreads();
  if ((t & 63) == 0) red[t >> 6] = v;
  __syncthreads();
  float r = (red[0] + red[1]) + (red[2] + red[3]);
  __syncthreads();
  return r;
}
__device__ __forceinline__ float blockMax256(float v, float* red, int t){
  #pragma unroll
  for (int off = 32; off > 0; off >>= 1) v = fmaxf(v, __shfl_down(v, off));
  __syncthreads();
  if ((t & 63) == 0) red[t >> 6] = v;
  __syncthreads();
  float r = fmaxf(fmaxf(red[0], red[1]), fmaxf(red[2], red[3]));
  __syncthreads();
  return r;
}
__device__ __forceinline__ int blockArgmax256(float v, int i, float* redf, int* redi, int t){
  #pragma unroll
  for (int off = 32; off > 0; off >>= 1){
    float ov = __shfl_down(v, off);
    int   oi = __shfl_down(i, off);
    if (ov > v || (ov == v && oi < i)){ v = ov; i = oi; }
  }
  __syncthreads();
  if ((t & 63) == 0){ redf[t >> 6] = v; redi[t >> 6] = i; }
  __syncthreads();
  float bv = redf[0]; int bi = redi[0];
  #pragma unroll
  for (int wv = 1; wv < 4; wv++){
    float ov = redf[wv]; int oi = redi[wv];
    if (ov > bv || (ov == bv && oi < bi)){ bv = ov; bi = oi; }
  }
  __syncthreads();
  return bi;
}

// ---- norms + wimgT (4 blocks x 1024 threads)
__global__ __launch_bounds__(1024) void norms_kernel(
    const float* __restrict__ wimg, const float* __restrict__ wrec,
    const float* __restrict__ wrec2, float* __restrict__ c1norm,
    float* __restrict__ w3norm, float* __restrict__ w6norm,
    float* __restrict__ wimgT){
  int t = threadIdx.x;
  if (blockIdx.x == 0){
    __shared__ float red[8][128];
    int k = t & 127, sl = t >> 7;
    float s = 0.f;
    int g0 = sl * (G_/8);
    for (int g = g0; g < g0 + G_/8; g++){
      float v = wimg[g*K_ + k]; s += v*v;
    }
    red[sl][k] = s;
    __syncthreads();
    if (t < 128){
      float r = 0.f;
      #pragma unroll
      for (int i = 0; i < 8; i++) r += red[i][t];
      c1norm[t] = r;
    }
  } else if (blockIdx.x == 1){
    int wave = t >> 6, lane = t & 63;
    for (int k = wave; k < K_; k += 16){
      float v0 = wrec[k*E2_ + lane], v1 = wrec[k*E2_ + 64 + lane];
      float s = v0*v0 + v1*v1;
      #pragma unroll
      for (int off = 32; off > 0; off >>= 1) s += __shfl_down(s, off);
      if (lane == 0) w3norm[k] = s;
    }
  } else if (blockIdx.x == 2){
    int wave = t >> 6, lane = t & 63;
    for (int j = wave; j < J_; j += 16){
      float v0 = wrec2[j*E2_ + lane], v1 = wrec2[j*E2_ + 64 + lane];
      float s = v0*v0 + v1*v1;
      #pragma unroll
      for (int off = 32; off > 0; off >>= 1) s += __shfl_down(s, off);
      if (lane == 0) w6norm[j] = s;
    }
  } else {
    // wimgT[k*G + g] = wimg[g*K + k]; coalesced writes, scattered (L2-hit) reads
    for (int n = t; n < K_*G_; n += 1024){
      int k = n >> 9, g = n & 511;
      wimgT[n] = wimg[g*K_ + k];
    }
  }
}

// ---- tables partials over g (+ fused W2 bf16 store): n = k*129+j
__global__ __launch_bounds__(128) void tables_part_kernel(
    const float* __restrict__ wimg2, const float* __restrict__ wimg,
    float* __restrict__ sqp, float* __restrict__ crp,
    unsigned short* __restrict__ W2){
  int n  = blockIdx.x * 128 + threadIdx.x;   // [0,16512)
  int gs = blockIdx.y;
  int k = n / J_;
  float s0=0,s1=0,s2=0,s3=0, c0=0,c1=0,c2=0,c3=0;
  int gbase = gs * (G_/GS_);
  #pragma unroll 2
  for (int g = gbase; g < gbase + G_/GS_; g += 4){
    float w0 = wimg2[(size_t)(g  )*KK_ + n];
    float w1 = wimg2[(size_t)(g+1)*KK_ + n];
    float w2 = wimg2[(size_t)(g+2)*KK_ + n];
    float w3 = wimg2[(size_t)(g+3)*KK_ + n];
    W2[(size_t)(g  )*KKP_ + n] = f2bf(w0);
    W2[(size_t)(g+1)*KKP_ + n] = f2bf(w1);
    W2[(size_t)(g+2)*KKP_ + n] = f2bf(w2);
    W2[(size_t)(g+3)*KKP_ + n] = f2bf(w3);
    s0 += w0*w0; s1 += w1*w1; s2 += w2*w2; s3 += w3*w3;
    c0 += wimg[(g  )*K_ + k]*w0;
    c1 += wimg[(g+1)*K_ + k]*w1;
    c2 += wimg[(g+2)*K_ + k]*w2;
    c3 += wimg[(g+3)*K_ + k]*w3;
  }
  sqp[(size_t)gs*KK_ + n] = (s0+s1)+(s2+s3);
  crp[(size_t)gs*KK_ + n] = (c0+c1)+(c2+c3);
}
__global__ __launch_bounds__(128) void tables_reduce_kernel(
    const float* __restrict__ sqp, const float* __restrict__ crp,
    float* __restrict__ sq2, float* __restrict__ cross){
  int n = blockIdx.x * 128 + threadIdx.x;
  float s = 0.f, c = 0.f;
  #pragma unroll
  for (int gs = 0; gs < GS_; gs++){
    s += sqp[(size_t)gs*KK_ + n];
    c += crp[(size_t)gs*KK_ + n];
  }
  sq2[n] = s; cross[n] = c;
}

// ---- W2 tail columns: [KK_,KKE_) = wimg, [KKE_,KKP_) = 0
__global__ __launch_bounds__(128) void w2tail_kernel(
    const float* __restrict__ wimg, unsigned short* __restrict__ W2){
  int g = blockIdx.x, t = threadIdx.x;
  unsigned short* dst = W2 + (size_t)g * KKP_;
  dst[KK_ + t]        = f2bf(wimg[g*K_ + t]);
  dst[KKE_ + t]       = 0;
  dst[KKE_ + 128 + t] = 0;
}

// ---- encode+decode probabilities per b (256 thr); writes R row (bf16)
__global__ __launch_bounds__(256) void encdec_kernel(
    const float* __restrict__ img,  const float* __restrict__ wimgT,
    const float* __restrict__ wrec, const float* __restrict__ wrec2,
    const unsigned short* __restrict__ W2,
    const float* __restrict__ c1norm, const float* __restrict__ w3norm,
    const float* __restrict__ w6norm, const float* __restrict__ sq2,
    const float* __restrict__ cross, unsigned short* __restrict__ Rm){
  __shared__ __align__(16) float simg[G_];
  __shared__ float sp[K_];                 // p (xp_d)
  __shared__ float sqv[J_];                // xp2, then q (xp2_d)
  __shared__ __align__(16) float slat[E2_];
  __shared__ float sd1[K_];
  __shared__ float sh2[2][K_];             // half-partials
  __shared__ float xtra[2];                // j=128 extras
  __shared__ float redf[4];
  __shared__ int   redi[4];

  int t = threadIdx.x;
  int b = blockIdx.x;
  int tt = t & 127, h = t >> 7;

  // -- stage 1: xp1 = softmax_k( -(||img-c_k||^2)/512 )
  simg[t      ] = img[b*G_ + t      ];
  simg[t + 256] = img[b*G_ + t + 256];
  __syncthreads();
  float a0 = simg[t], a1 = simg[t+256];
  float imgnorm = blockSum256(a0*a0 + a1*a1, redf, t);

  {
    const float4* wrow = (const float4*)(wimgT + (size_t)tt*G_ + h*256);
    const float4* srow = (const float4*)(simg + h*256);
    float s0=0,s1=0,s2=0,s3=0;
    #pragma unroll 4
    for (int i = 0; i < 64; i++){
      float4 wv = wrow[i], sv = srow[i];
      s0 += wv.x*sv.x; s1 += wv.y*sv.y; s2 += wv.z*sv.z; s3 += wv.w*sv.w;
    }
    sh2[h][tt] = (s0+s1)+(s2+s3);
  }
  __syncthreads();
  float d1 = sh2[0][tt] + sh2[1][tt];
  if (h == 0) sd1[tt] = d1;
  float xh1 = -(imgnorm - 2.f*d1 + c1norm[tt]) * (1.f/512.f);
  float m1 = blockMax256(xh1, redf, t);
  float ex1 = expf(xh1 - m1);
  float s1 = blockSum256((h == 0) ? ex1 : 0.f, redf, t);
  if (h == 0) sp[tt] = ex1 / s1;
  __syncthreads();

  // -- stage 2: lat[e=tt] = sum_k xp1[k]*wrec[k][e], k split by half
  {
    float l0=0,l1=0;
    int k0 = h * 64;
    for (int k = k0; k < k0 + 64; k += 2){
      l0 += sp[k  ] * wrec[(k  )*E2_ + tt];
      l1 += sp[k+1] * wrec[(k+1)*E2_ + tt];
    }
    sh2[h][tt] = l0 + l1;
  }
  __syncthreads();
  float lat = sh2[0][tt] + sh2[1][tt];
  if (h == 0) slat[tt] = lat;
  float latnorm = blockSum256((h == 0) ? lat*lat : 0.f, redf, t);

  // -- stage 3: d3[k=tt] = sum_e lat[e]*wrec[k][e], row-streamed float4, e split
  {
    const float4* rrow = (const float4*)(wrec + (size_t)tt*E2_ + h*64);
    const float4* lrow = (const float4*)(slat + h*64);
    float s0=0,s1=0,s2=0,s3=0;
    #pragma unroll 4
    for (int i = 0; i < 16; i++){
      float4 wv = rrow[i], lv = lrow[i];
      s0 += wv.x*lv.x; s1 += wv.y*lv.y; s2 += wv.z*lv.z; s3 += wv.w*lv.w;
    }
    sh2[h][tt] = (s0+s1)+(s2+s3);
  }
  __syncthreads();
  float d3 = sh2[0][tt] + sh2[1][tt];
  float xh3 = -(latnorm - 2.f*d3 + w3norm[tt]) * (1.f/128.f);
  float m3 = blockMax256(xh3, redf, t);
  float ex3 = expf(xh3 - m3);
  float s3 = blockSum256((h == 0) ? ex3 : 0.f, redf, t);
  if (h == 0) sp[tt] = ex3 / s3;          // final p (xp_d)
  int idxb = blockArgmax256(xh3, tt, redf, redi, t);
  float dsq = imgnorm - 2.f*sd1[idxb] + c1norm[idxb];

  // -- stage 5: di[j] = sum_g simg[g]*W2[g][idxb*J+j]; j=tt (g split), j=128 via wave0
  {
    const unsigned short* Wb = W2 + (size_t)idxb * J_ + tt;
    float s0=0,s1=0,s2=0,s3=0;
    int g0 = h * 256;
    for (int g = g0; g < g0 + 256; g += 4){
      s0 += simg[g  ] * bf2f(Wb[(size_t)(g  )*KKP_]);
      s1 += simg[g+1] * bf2f(Wb[(size_t)(g+1)*KKP_]);
      s2 += simg[g+2] * bf2f(Wb[(size_t)(g+2)*KKP_]);
      s3 += simg[g+3] * bf2f(Wb[(size_t)(g+3)*KKP_]);
    }
    sh2[h][tt] = (s0+s1)+(s2+s3);
  }
  if (t < 64){
    const unsigned short* Wb8 = W2 + (size_t)idxb * J_ + 128;
    float s = 0.f;
    #pragma unroll
    for (int m = 0; m < 8; m++){
      int g = t + 64*m;
      s += simg[g] * bf2f(Wb8[(size_t)g * KKP_]);
    }
    #pragma unroll
    for (int off = 32; off > 0; off >>= 1) s += __shfl_down(s, off);
    if (t == 0) xtra[0] = s;
  }
  __syncthreads();
  float xh2 = -3e38f;
  if (t < J_){
    float di = (t < 128) ? (sh2[0][t] + sh2[1][t]) : xtra[0];
    int nb = idxb*J_ + t;
    xh2 = -(dsq - 2.f*(di - cross[nb]) + sq2[nb]) * (1.f/512.f);
  }
  float m2 = blockMax256(xh2, redf, t);
  float ea = (t < J_) ? expf(xh2 - m2) : 0.f;
  float s2 = blockSum256(ea, redf, t);
  if (t < J_) sqv[t] = ea / s2;
  __syncthreads();

  // -- stage 6: lat2[e=tt] = sum_j xp2[j]*wrec2[j][e], j split 65/64
  {
    float l = 0.f;
    int j0 = h ? 65 : 0, j1 = h ? J_ : 65;
    for (int j = j0; j < j1; j++)
      l += sqv[j] * wrec2[j*E2_ + tt];
    sh2[h][tt] = l;
  }
  __syncthreads();
  float lat2 = sh2[0][tt] + sh2[1][tt];
  if (h == 0) slat[tt] = lat2;
  float l2n = blockSum256((h == 0) ? lat2*lat2 : 0.f, redf, t);

  // -- stage 7: d6[j=tt] = sum_e lat2[e]*wrec2[j][e], row-streamed float4; j=128 via wave0
  {
    const float4* rrow = (const float4*)(wrec2 + (size_t)tt*E2_ + h*64);
    const float4* lrow = (const float4*)(slat + h*64);
    float s0=0,s1=0,s2=0,s3=0;
    #pragma unroll 4
    for (int i = 0; i < 16; i++){
      float4 wv = rrow[i], lv = lrow[i];
      s0 += wv.x*lv.x; s1 += wv.y*lv.y; s2 += wv.z*lv.z; s3 += wv.w*lv.w;
    }
    sh2[h][tt] = (s0+s1)+(s2+s3);
  }
  if (t < 64){
    float s = slat[t]*wrec2[128*E2_ + t] + slat[t+64]*wrec2[128*E2_ + 64 + t];
    #pragma unroll
    for (int off = 32; off > 0; off >>= 1) s += __shfl_down(s, off);
    if (t == 0) xtra[1] = s;
  }
  __syncthreads();
  float xh6 = -3e38f;
  if (t < J_){
    float d6 = (t < 128) ? (sh2[0][t] + sh2[1][t]) : xtra[1];
    xh6 = -(l2n - 2.f*d6 + w6norm[t]) * (1.f/128.f);
  }
  float m6 = blockMax256(xh6, redf, t);
  float e6 = (t < J_) ? expf(xh6 - m6) : 0.f;
  float s6 = blockSum256(e6, redf, t);
  if (t < J_) sqv[t] = e6 / s6;
  __syncthreads();

  // -- R fill: [0,KK_): p_k*q_j ; [KK_,KKE_): p ; rest 0  (incremental k,j)
  unsigned short* Rrow = Rm + (size_t)b * KKP_;
  int k = (t >= J_) ? 1 : 0;
  int j = t - k*J_;
  for (int kk = t; kk < KKP_; kk += 256){
    float v = 0.f;
    if (kk < KK_)        v = sp[k] * sqv[j];
    else if (kk < KKE_)  v = sp[kk - KK_];
    Rrow[kk] = f2bf(v);
    if (j < 2){ j += 127; k += 1; } else { j -= 2; k += 2; }
  }
}

// ---- big einsum as bf16 NT GEMM with split-K:
// part[z][b][g] = sum_{kk in chunk z} R[b,kk]*W2[g,kk]
__global__ __launch_bounds__(256) void gemm_kernel(
    const unsigned short* __restrict__ Rm, const unsigned short* __restrict__ W2,
    float* __restrict__ part){
  __shared__ __align__(16) unsigned int lds[2*128*20];   // 80B-stride rows, A then B
  unsigned int* lA = lds;
  unsigned int* lB = lds + 128*20;
  int tid = threadIdx.x;
  int l = tid & 63;
  int w = tid >> 6;
  int wr = (w >> 1) * 64, wc = (w & 1) * 64;
  int b0 = blockIdx.y * 128, g0 = blockIdx.x * 128;
  size_t kkbase = (size_t)blockIdx.z * KCHUNK;

  int srow = tid >> 2, scol = tid & 3;
  const unsigned short* pa = Rm + (size_t)(b0 + srow)*KKP_ + kkbase + scol*8;
  const unsigned short* pb = W2 + (size_t)(g0 + srow)*KKP_ + kkbase + scol*8;
  const size_t half = (size_t)64 * KKP_;
  unsigned int woff = srow*20 + scol*4;

  int lrow = l & 15, lko = (l >> 4) << 2;

  f32x4 zero4 = {0.f, 0.f, 0.f, 0.f};
  f32x4 acc[4][4];
  #pragma unroll
  for (int mi = 0; mi < 4; mi++)
    #pragma unroll
    for (int ni = 0; ni < 4; ni++) acc[mi][ni] = zero4;

  for (int s = 0; s < KSTEPS; s++){
    uint4 va0 = *(const uint4*)pa;
    uint4 va1 = *(const uint4*)(pa + half);
    uint4 vb0 = *(const uint4*)pb;
    uint4 vb1 = *(const uint4*)(pb + half);
    pa += BK_; pb += BK_;
    __syncthreads();
    *(uint4*)(lA + woff)          = va0;
    *(uint4*)(lA + woff + 64*20)  = va1;
    *(uint4*)(lB + woff)          = vb0;
    *(uint4*)(lB + woff + 64*20)  = vb1;
    __syncthreads();
    short8 af[4], bfv[4];
    #pragma unroll
    for (int mi = 0; mi < 4; mi++)
      af[mi] = *(const short8*)(lA + (wr + mi*16 + lrow)*20 + lko);
    #pragma unroll
    for (int ni = 0; ni < 4; ni++)
      bfv[ni] = *(const short8*)(lB + (wc + ni*16 + lrow)*20 + lko);
    #pragma unroll
    for (int mi = 0; mi < 4; mi++)
      #pragma unroll
      for (int ni = 0; ni < 4; ni++)
        acc[mi][ni] = __builtin_amdgcn_mfma_f32_16x16x32_bf16(af[mi], bfv[ni], acc[mi][ni], 0, 0, 0);
  }

  float* P = part + ((size_t)blockIdx.z * B_ + b0) * G_ + g0;
  int rh = (l >> 4) << 2, cl = l & 15;
  #pragma unroll
  for (int mi = 0; mi < 4; mi++)
    #pragma unroll
    for (int ni = 0; ni < 4; ni++)
      #pragma unroll
      for (int r = 0; r < 4; r++){
        int row = wr + mi*16 + rh + r;
        int col = wc + ni*16 + cl;
        P[(size_t)row*G_ + col] = acc[mi][ni][r];
      }
}

// ---- loss[b] = mean_g ( (sum_z part[z][b][g]) - img[b][g] )^2
__global__ __launch_bounds__(128) void loss_kernel(
    const float* __restrict__ img, const float* __restrict__ part,
    float* __restrict__ out){
  __shared__ float redf[2];
  int t = threadIdx.x, b = blockIdx.x;
  float acc = 0.f;
  for (int g = t; g < G_; g += 128){
    float x = 0.f;
    #pragma unroll
    for (int z = 0; z < SPLITS; z++)
      x += part[((size_t)z*B_ + b)*G_ + g];
    float d = x - img[b*G_ + g];
    acc += d*d;
  }
  #pragma unroll
  for (int off = 32; off > 0; off >>= 1) acc += __shfl_down(acc, off);
  __syncthreads();
  if ((t & 63) == 0) redf[t >> 6] = acc;
  __syncthreads();
  if (t == 0) out[b] = (redf[0] + redf[1]) * (1.f/512.f);
}

extern "C" void kernel_launch(void* const* d_in, const int* in_sizes, int n_in,
                              void* d_out, int out_size, void* d_ws, size_t ws_size,
                              hipStream_t stream){
  (void)in_sizes; (void)n_in; (void)out_size; (void)ws_size;
  const float* img   = (const float*)d_in[0];
  const float* wimg  = (const float*)d_in[1];
  const float* wrec  = (const float*)d_in[2];
  const float* wrec2 = (const float*)d_in[3];
  const float* wimg2 = (const float*)d_in[4];
  float* out = (float*)d_out;

  char* ws = (char*)d_ws;
  size_t off = 0;
  auto alloc = [&](size_t bytes) -> void* {
    void* p = ws + off;
    off += (bytes + 255) & ~(size_t)255;
    return p;
  };
  unsigned short* W2   = (unsigned short*)alloc((size_t)G_ * KKP_ * 2);
  unsigned short* Rm   = (unsigned short*)alloc((size_t)B_ * KKP_ * 2);
  float* part   = (float*)alloc((size_t)SPLITS * B_ * G_ * 4);
  float* sqp    = (float*)alloc((size_t)GS_ * KK_ * 4);
  float* crp    = (float*)alloc((size_t)GS_ * KK_ * 4);
  float* sq2    = (float*)alloc((size_t)KK_ * 4);
  float* cross  = (float*)alloc((size_t)KK_ * 4);
  float* c1norm = (float*)alloc(K_ * 4);
  float* w3norm = (float*)alloc(K_ * 4);
  float* w6norm = (float*)alloc(J_ * 4);
  float* wimgT  = (float*)alloc((size_t)K_ * G_ * 4);

  norms_kernel<<<dim3(4), dim3(1024), 0, stream>>>(wimg, wrec, wrec2, c1norm, w3norm, w6norm, wimgT);
  tables_part_kernel<<<dim3(129, GS_), dim3(128), 0, stream>>>(wimg2, wimg, sqp, crp, W2);
  tables_reduce_kernel<<<dim3(129), dim3(128), 0, stream>>>(sqp, crp, sq2, cross);
  w2tail_kernel<<<dim3(512), dim3(128), 0, stream>>>(wimg, W2);
  encdec_kernel<<<dim3(1024), dim3(256), 0, stream>>>(img, wimgT, wrec, wrec2, W2,
      c1norm, w3norm, w6norm, sq2, cross, Rm);
  gemm_kernel<<<dim3(4, 8, SPLITS), dim3(256), 0, stream>>>(Rm, W2, part);
  loss_kernel<<<dim3(1024), dim3(128), 0, stream>>>(img, part, out);
}

// Round 6
// 135.366 us; speedup vs baseline: 1.3499x; 1.3499x over previous
//
#include <hip/hip_runtime.h>

#define B_   1024
#define G_   512
#define K_   128
#define J_   129
#define E2_  128
#define KK_  16512      /* K_*J_ */
#define KKE_ 16640      /* KK_ + K_ (appended wimg columns) */
#define KKP_ 16896      /* padded: SPLITS*KCHUNK */
#define SPLITS 16
#define KCHUNK 1056     /* KKP_/SPLITS */
#define BK_  32
#define KSTEPS 33       /* KCHUNK/BK_ */
#define GS_  8          /* g-splits for table partials */

using short8 = __attribute__((ext_vector_type(8))) short;
using f32x4  = __attribute__((ext_vector_type(4))) float;

__device__ __forceinline__ float bf2f(unsigned short h){
  return __uint_as_float(((unsigned int)h) << 16);
}
__device__ __forceinline__ unsigned short f2bf(float f){
  unsigned int u = __float_as_uint(f);
  u += 0x7fffu + ((u >> 16) & 1u);          // round-to-nearest-even
  return (unsigned short)(u >> 16);
}

// ---- block (256-thread, 4-wave) reductions -------------------------------
__device__ __forceinline__ float blockSum256(float v, float* red, int t){
  #pragma unroll
  for (int off = 32; off > 0; off >>= 1) v += __shfl_down(v, off);
  __syncthreads();
  if ((t & 63) == 0) red[t >> 6] = v;
  __syncthreads();
  float r = (red[0] + red[1]) + (red[2] + red[3]);
  __syncthreads();
  return r;
}
__device__ __forceinline__ float blockMax256(float v, float* red, int t){
  #pragma unroll
  for (int off = 32; off > 0; off >>= 1) v = fmaxf(v, __shfl_down(v, off));
  __syncthreads();
  if ((t & 63) == 0) red[t >> 6] = v;
  __syncthreads();
  float r = fmaxf(fmaxf(red[0], red[1]), fmaxf(red[2], red[3]));
  __syncthreads();
  return r;
}
__device__ __forceinline__ int blockArgmax256(float v, int i, float* redf, int* redi, int t){
  #pragma unroll
  for (int off = 32; off > 0; off >>= 1){
    float ov = __shfl_down(v, off);
    int   oi = __shfl_down(i, off);
    if (ov > v || (ov == v && oi < i)){ v = ov; i = oi; }
  }
  __syncthreads();
  if ((t & 63) == 0){ redf[t >> 6] = v; redi[t >> 6] = i; }
  __syncthreads();
  float bv = redf[0]; int bi = redi[0];
  #pragma unroll
  for (int wv = 1; wv < 4; wv++){
    float ov = redf[wv]; int oi = redi[wv];
    if (ov > bv || (ov == bv && oi < bi)){ bv = ov; bi = oi; }
  }
  __syncthreads();
  return bi;
}

// ---- norms + transposes (5 blocks x 1024 threads)
__global__ __launch_bounds__(1024) void norms_kernel(
    const float* __restrict__ wimg, const float* __restrict__ wrec,
    const float* __restrict__ wrec2, float* __restrict__ c1norm,
    float* __restrict__ w3norm, float* __restrict__ w6norm,
    float* __restrict__ wrecT, float* __restrict__ wrec2T){
  int t = threadIdx.x;
  if (blockIdx.x == 0){
    __shared__ float red[8][128];
    int k = t & 127, sl = t >> 7;
    float s = 0.f;
    int g0 = sl * (G_/8);
    for (int g = g0; g < g0 + G_/8; g++){
      float v = wimg[g*K_ + k]; s += v*v;
    }
    red[sl][k] = s;
    __syncthreads();
    if (t < 128){
      float r = 0.f;
      #pragma unroll
      for (int i = 0; i < 8; i++) r += red[i][t];
      c1norm[t] = r;
    }
  } else if (blockIdx.x == 1){
    int wave = t >> 6, lane = t & 63;
    for (int k = wave; k < K_; k += 16){
      float v0 = wrec[k*E2_ + lane], v1 = wrec[k*E2_ + 64 + lane];
      float s = v0*v0 + v1*v1;
      #pragma unroll
      for (int off = 32; off > 0; off >>= 1) s += __shfl_down(s, off);
      if (lane == 0) w3norm[k] = s;
    }
  } else if (blockIdx.x == 2){
    int wave = t >> 6, lane = t & 63;
    for (int j = wave; j < J_; j += 16){
      float v0 = wrec2[j*E2_ + lane], v1 = wrec2[j*E2_ + 64 + lane];
      float s = v0*v0 + v1*v1;
      #pragma unroll
      for (int off = 32; off > 0; off >>= 1) s += __shfl_down(s, off);
      if (lane == 0) w6norm[j] = s;
    }
  } else if (blockIdx.x == 3){
    for (int n = t; n < K_*E2_; n += 1024){
      int k = n >> 7, e = n & 127;
      wrecT[e*K_ + k] = wrec[n];
    }
  } else {
    for (int n = t; n < J_*E2_; n += 1024){
      int j = n >> 7, e = n & 127;
      wrec2T[e*J_ + j] = wrec2[n];
    }
  }
}

// ---- tables partials over g (+ fused W2 bf16 store): n = k*129+j
__global__ __launch_bounds__(128) void tables_part_kernel(
    const float* __restrict__ wimg2, const float* __restrict__ wimg,
    float* __restrict__ sqp, float* __restrict__ crp,
    unsigned short* __restrict__ W2){
  int n  = blockIdx.x * 128 + threadIdx.x;   // [0,16512)
  int gs = blockIdx.y;
  int k = n / J_;
  float s0=0,s1=0,s2=0,s3=0, c0=0,c1=0,c2=0,c3=0;
  int gbase = gs * (G_/GS_);
  #pragma unroll 2
  for (int g = gbase; g < gbase + G_/GS_; g += 4){
    float w0 = wimg2[(size_t)(g  )*KK_ + n];
    float w1 = wimg2[(size_t)(g+1)*KK_ + n];
    float w2 = wimg2[(size_t)(g+2)*KK_ + n];
    float w3 = wimg2[(size_t)(g+3)*KK_ + n];
    W2[(size_t)(g  )*KKP_ + n] = f2bf(w0);
    W2[(size_t)(g+1)*KKP_ + n] = f2bf(w1);
    W2[(size_t)(g+2)*KKP_ + n] = f2bf(w2);
    W2[(size_t)(g+3)*KKP_ + n] = f2bf(w3);
    s0 += w0*w0; s1 += w1*w1; s2 += w2*w2; s3 += w3*w3;
    c0 += wimg[(g  )*K_ + k]*w0;
    c1 += wimg[(g+1)*K_ + k]*w1;
    c2 += wimg[(g+2)*K_ + k]*w2;
    c3 += wimg[(g+3)*K_ + k]*w3;
  }
  sqp[(size_t)gs*KK_ + n] = (s0+s1)+(s2+s3);
  crp[(size_t)gs*KK_ + n] = (c0+c1)+(c2+c3);
}
__global__ __launch_bounds__(128) void tables_reduce_kernel(
    const float* __restrict__ sqp, const float* __restrict__ crp,
    float* __restrict__ sq2, float* __restrict__ cross){
  int n = blockIdx.x * 128 + threadIdx.x;
  float s = 0.f, c = 0.f;
  #pragma unroll
  for (int gs = 0; gs < GS_; gs++){
    s += sqp[(size_t)gs*KK_ + n];
    c += crp[(size_t)gs*KK_ + n];
  }
  sq2[n] = s; cross[n] = c;
}

// ---- W2 tail columns: [KK_,KKE_) = wimg, [KKE_,KKP_) = 0
__global__ __launch_bounds__(128) void w2tail_kernel(
    const float* __restrict__ wimg, unsigned short* __restrict__ W2){
  int g = blockIdx.x, t = threadIdx.x;
  unsigned short* dst = W2 + (size_t)g * KKP_;
  dst[KK_ + t]        = f2bf(wimg[g*K_ + t]);
  dst[KKE_ + t]       = 0;
  dst[KKE_ + 128 + t] = 0;
}

// ---- encode+decode probabilities per b (256 thr); writes R row (bf16)
__global__ __launch_bounds__(256) void encdec_kernel(
    const float* __restrict__ img,  const float* __restrict__ wimg,
    const float* __restrict__ wrec, const float* __restrict__ wrec2,
    const float* __restrict__ wrecT, const float* __restrict__ wrec2T,
    const unsigned short* __restrict__ W2,
    const float* __restrict__ c1norm, const float* __restrict__ w3norm,
    const float* __restrict__ w6norm, const float* __restrict__ sq2,
    const float* __restrict__ cross, unsigned short* __restrict__ Rm){
  __shared__ float simg[G_];
  __shared__ float sp[K_];                 // p (xp_d)
  __shared__ float sqv[J_];                // xp2, then q (xp2_d)
  __shared__ float slat[E2_];
  __shared__ float sd1[K_];
  __shared__ float sh2[2][K_];             // half-partials
  __shared__ float xtra[2];                // j=128 extras
  __shared__ float redf[4];
  __shared__ int   redi[4];

  int t = threadIdx.x;
  int b = blockIdx.x;
  int tt = t & 127, h = t >> 7;

  // -- stage 1: xp1 = softmax_k( -(||img-c_k||^2)/512 )
  simg[t      ] = img[b*G_ + t      ];
  simg[t + 256] = img[b*G_ + t + 256];
  __syncthreads();
  float a0 = simg[t], a1 = simg[t+256];
  float imgnorm = blockSum256(a0*a0 + a1*a1, redf, t);

  {
    // d1[k=tt]: lanes tt consecutive -> coalesced column loads; g-half split
    float d0=0,d1v=0,d2=0,d3v=0;
    int g0 = h * 256;
    const float* wcol = wimg + tt;
    for (int g = g0; g < g0 + 256; g += 4){
      d0  += simg[g  ] * wcol[(g  )*K_];
      d1v += simg[g+1] * wcol[(g+1)*K_];
      d2  += simg[g+2] * wcol[(g+2)*K_];
      d3v += simg[g+3] * wcol[(g+3)*K_];
    }
    sh2[h][tt] = (d0+d1v)+(d2+d3v);
  }
  __syncthreads();
  float d1 = sh2[0][tt] + sh2[1][tt];
  if (h == 0) sd1[tt] = d1;
  float xh1 = -(imgnorm - 2.f*d1 + c1norm[tt]) * (1.f/512.f);
  float m1 = blockMax256(xh1, redf, t);
  float ex1 = expf(xh1 - m1);
  float s1 = blockSum256((h == 0) ? ex1 : 0.f, redf, t);
  if (h == 0) sp[tt] = ex1 / s1;
  __syncthreads();

  // -- stage 2: lat[e=tt] = sum_k xp1[k]*wrec[k][e], k split by half (coalesced)
  {
    float l0=0,l1=0;
    int k0 = h * 64;
    for (int k = k0; k < k0 + 64; k += 2){
      l0 += sp[k  ] * wrec[(k  )*E2_ + tt];
      l1 += sp[k+1] * wrec[(k+1)*E2_ + tt];
    }
    sh2[h][tt] = l0 + l1;
  }
  __syncthreads();
  float lat = sh2[0][tt] + sh2[1][tt];
  if (h == 0) slat[tt] = lat;
  float latnorm = blockSum256((h == 0) ? lat*lat : 0.f, redf, t);

  // -- stage 3: d3[k=tt] = sum_e lat[e]*wrecT[e][k], e split by half (coalesced)
  {
    float l0=0,l1=0;
    int e0 = h * 64;
    const float* rT = wrecT + tt;
    for (int e = e0; e < e0 + 64; e += 2){
      l0 += slat[e  ] * rT[(e  )*K_];
      l1 += slat[e+1] * rT[(e+1)*K_];
    }
    sh2[h][tt] = l0 + l1;
  }
  __syncthreads();
  float d3 = sh2[0][tt] + sh2[1][tt];
  float xh3 = -(latnorm - 2.f*d3 + w3norm[tt]) * (1.f/128.f);
  float m3 = blockMax256(xh3, redf, t);
  float ex3 = expf(xh3 - m3);
  float s3 = blockSum256((h == 0) ? ex3 : 0.f, redf, t);
  if (h == 0) sp[tt] = ex3 / s3;          // final p (xp_d)
  int idxb = blockArgmax256(xh3, tt, redf, redi, t);
  float dsq = imgnorm - 2.f*sd1[idxb] + c1norm[idxb];

  // -- stage 5: di[j] = sum_g simg[g]*W2[g][idxb*J+j]; j=tt, g-half split; j=128 via wave0
  {
    const unsigned short* Wb = W2 + (size_t)idxb * J_ + tt;
    float s0=0,s1=0,s2=0,s3=0;
    int g0 = h * 256;
    for (int g = g0; g < g0 + 256; g += 4){
      s0 += simg[g  ] * bf2f(Wb[(size_t)(g  )*KKP_]);
      s1 += simg[g+1] * bf2f(Wb[(size_t)(g+1)*KKP_]);
      s2 += simg[g+2] * bf2f(Wb[(size_t)(g+2)*KKP_]);
      s3 += simg[g+3] * bf2f(Wb[(size_t)(g+3)*KKP_]);
    }
    sh2[h][tt] = (s0+s1)+(s2+s3);
  }
  if (t < 64){
    const unsigned short* Wb8 = W2 + (size_t)idxb * J_ + 128;
    float s = 0.f;
    #pragma unroll
    for (int m = 0; m < 8; m++){
      int g = t + 64*m;
      s += simg[g] * bf2f(Wb8[(size_t)g * KKP_]);
    }
    #pragma unroll
    for (int off = 32; off > 0; off >>= 1) s += __shfl_down(s, off);
    if (t == 0) xtra[0] = s;
  }
  __syncthreads();
  float xh2 = -3e38f;
  if (t < J_){
    float di = (t < 128) ? (sh2[0][t] + sh2[1][t]) : xtra[0];
    int nb = idxb*J_ + t;
    xh2 = -(dsq - 2.f*(di - cross[nb]) + sq2[nb]) * (1.f/512.f);
  }
  float m2 = blockMax256(xh2, redf, t);
  float ea = (t < J_) ? expf(xh2 - m2) : 0.f;
  float s2 = blockSum256(ea, redf, t);
  if (t < J_) sqv[t] = ea / s2;
  __syncthreads();

  // -- stage 6: lat2[e=tt] = sum_j xp2[j]*wrec2[j][e], j split 65/64 (coalesced)
  {
    float l = 0.f;
    int j0 = h ? 65 : 0, j1 = h ? J_ : 65;
    for (int j = j0; j < j1; j++)
      l += sqv[j] * wrec2[j*E2_ + tt];
    sh2[h][tt] = l;
  }
  __syncthreads();
  float lat2 = sh2[0][tt] + sh2[1][tt];
  if (h == 0) slat[tt] = lat2;
  float l2n = blockSum256((h == 0) ? lat2*lat2 : 0.f, redf, t);

  // -- stage 7: d6[j=tt] = sum_e lat2[e]*wrec2T[e][j], e-half split (coalesced); j=128 via wave0
  {
    float l0=0,l1=0;
    int e0 = h * 64;
    const float* rT = wrec2T + tt;
    for (int e = e0; e < e0 + 64; e += 2){
      l0 += slat[e  ] * rT[(e  )*J_];
      l1 += slat[e+1] * rT[(e+1)*J_];
    }
    sh2[h][tt] = l0 + l1;
  }
  if (t < 64){
    float s = slat[t]*wrec2T[t*J_ + 128] + slat[t+64]*wrec2T[(t+64)*J_ + 128];
    #pragma unroll
    for (int off = 32; off > 0; off >>= 1) s += __shfl_down(s, off);
    if (t == 0) xtra[1] = s;
  }
  __syncthreads();
  float xh6 = -3e38f;
  if (t < J_){
    float d6 = (t < 128) ? (sh2[0][t] + sh2[1][t]) : xtra[1];
    xh6 = -(l2n - 2.f*d6 + w6norm[t]) * (1.f/128.f);
  }
  float m6 = blockMax256(xh6, redf, t);
  float e6 = (t < J_) ? expf(xh6 - m6) : 0.f;
  float s6 = blockSum256(e6, redf, t);
  if (t < J_) sqv[t] = e6 / s6;
  __syncthreads();

  // -- R fill: [0,KK_): p_k*q_j ; [KK_,KKE_): p ; rest 0  (incremental k,j)
  unsigned short* Rrow = Rm + (size_t)b * KKP_;
  int k = (t >= J_) ? 1 : 0;
  int j = t - k*J_;
  for (int kk = t; kk < KKP_; kk += 256){
    float v = 0.f;
    if (kk < KK_)        v = sp[k] * sqv[j];
    else if (kk < KKE_)  v = sp[kk - KK_];
    Rrow[kk] = f2bf(v);
    if (j < 2){ j += 127; k += 1; } else { j -= 2; k += 2; }
  }
}

// ---- big einsum as bf16 NT GEMM with split-K:
// part[z][b][g] = sum_{kk in chunk z} R[b,kk]*W2[g,kk]
__global__ __launch_bounds__(256) void gemm_kernel(
    const unsigned short* __restrict__ Rm, const unsigned short* __restrict__ W2,
    float* __restrict__ part){
  __shared__ __align__(16) unsigned int lds[2*128*20];   // 80B-stride rows, A then B
  unsigned int* lA = lds;
  unsigned int* lB = lds + 128*20;
  int tid = threadIdx.x;
  int l = tid & 63;
  int w = tid >> 6;
  int wr = (w >> 1) * 64, wc = (w & 1) * 64;
  int b0 = blockIdx.y * 128, g0 = blockIdx.x * 128;
  size_t kkbase = (size_t)blockIdx.z * KCHUNK;

  int srow = tid >> 2, scol = tid & 3;
  const unsigned short* pa = Rm + (size_t)(b0 + srow)*KKP_ + kkbase + scol*8;
  const unsigned short* pb = W2 + (size_t)(g0 + srow)*KKP_ + kkbase + scol*8;
  const size_t half = (size_t)64 * KKP_;
  unsigned int woff = srow*20 + scol*4;

  int lrow = l & 15, lko = (l >> 4) << 2;

  f32x4 zero4 = {0.f, 0.f, 0.f, 0.f};
  f32x4 acc[4][4];
  #pragma unroll
  for (int mi = 0; mi < 4; mi++)
    #pragma unroll
    for (int ni = 0; ni < 4; ni++) acc[mi][ni] = zero4;

  for (int s = 0; s < KSTEPS; s++){
    uint4 va0 = *(const uint4*)pa;
    uint4 va1 = *(const uint4*)(pa + half);
    uint4 vb0 = *(const uint4*)pb;
    uint4 vb1 = *(const uint4*)(pb + half);
    pa += BK_; pb += BK_;
    __syncthreads();
    *(uint4*)(lA + woff)          = va0;
    *(uint4*)(lA + woff + 64*20)  = va1;
    *(uint4*)(lB + woff)          = vb0;
    *(uint4*)(lB + woff + 64*20)  = vb1;
    __syncthreads();
    short8 af[4], bfv[4];
    #pragma unroll
    for (int mi = 0; mi < 4; mi++)
      af[mi] = *(const short8*)(lA + (wr + mi*16 + lrow)*20 + lko);
    #pragma unroll
    for (int ni = 0; ni < 4; ni++)
      bfv[ni] = *(const short8*)(lB + (wc + ni*16 + lrow)*20 + lko);
    #pragma unroll
    for (int mi = 0; mi < 4; mi++)
      #pragma unroll
      for (int ni = 0; ni < 4; ni++)
        acc[mi][ni] = __builtin_amdgcn_mfma_f32_16x16x32_bf16(af[mi], bfv[ni], acc[mi][ni], 0, 0, 0);
  }

  float* P = part + ((size_t)blockIdx.z * B_ + b0) * G_ + g0;
  int rh = (l >> 4) << 2, cl = l & 15;
  #pragma unroll
  for (int mi = 0; mi < 4; mi++)
    #pragma unroll
    for (int ni = 0; ni < 4; ni++)
      #pragma unroll
      for (int r = 0; r < 4; r++){
        int row = wr + mi*16 + rh + r;
        int col = wc + ni*16 + cl;
        P[(size_t)row*G_ + col] = acc[mi][ni][r];
      }
}

// ---- loss[b] = mean_g ( (sum_z part[z][b][g]) - img[b][g] )^2
__global__ __launch_bounds__(128) void loss_kernel(
    const float* __restrict__ img, const float* __restrict__ part,
    float* __restrict__ out){
  __shared__ float redf[2];
  int t = threadIdx.x, b = blockIdx.x;
  float acc = 0.f;
  for (int g = t; g < G_; g += 128){
    float x = 0.f;
    #pragma unroll
    for (int z = 0; z < SPLITS; z++)
      x += part[((size_t)z*B_ + b)*G_ + g];
    float d = x - img[b*G_ + g];
    acc += d*d;
  }
  #pragma unroll
  for (int off = 32; off > 0; off >>= 1) acc += __shfl_down(acc, off);
  __syncthreads();
  if ((t & 63) == 0) redf[t >> 6] = acc;
  __syncthreads();
  if (t == 0) out[b] = (redf[0] + redf[1]) * (1.f/512.f);
}

extern "C" void kernel_launch(void* const* d_in, const int* in_sizes, int n_in,
                              void* d_out, int out_size, void* d_ws, size_t ws_size,
                              hipStream_t stream){
  (void)in_sizes; (void)n_in; (void)out_size; (void)ws_size;
  const float* img   = (const float*)d_in[0];
  const float* wimg  = (const float*)d_in[1];
  const float* wrec  = (const float*)d_in[2];
  const float* wrec2 = (const float*)d_in[3];
  const float* wimg2 = (const float*)d_in[4];
  float* out = (float*)d_out;

  char* ws = (char*)d_ws;
  size_t off = 0;
  auto alloc = [&](size_t bytes) -> void* {
    void* p = ws + off;
    off += (bytes + 255) & ~(size_t)255;
    return p;
  };
  unsigned short* W2   = (unsigned short*)alloc((size_t)G_ * KKP_ * 2);
  unsigned short* Rm   = (unsigned short*)alloc((size_t)B_ * KKP_ * 2);
  float* part   = (float*)alloc((size_t)SPLITS * B_ * G_ * 4);
  float* sqp    = (float*)alloc((size_t)GS_ * KK_ * 4);
  float* crp    = (float*)alloc((size_t)GS_ * KK_ * 4);
  float* sq2    = (float*)alloc((size_t)KK_ * 4);
  float* cross  = (float*)alloc((size_t)KK_ * 4);
  float* c1norm = (float*)alloc(K_ * 4);
  float* w3norm = (float*)alloc(K_ * 4);
  float* w6norm = (float*)alloc(J_ * 4);
  float* wrecT  = (float*)alloc((size_t)K_ * E2_ * 4);
  float* wrec2T = (float*)alloc((size_t)J_ * E2_ * 4);

  norms_kernel<<<dim3(5), dim3(1024), 0, stream>>>(wimg, wrec, wrec2, c1norm, w3norm, w6norm, wrecT, wrec2T);
  tables_part_kernel<<<dim3(129, GS_), dim3(128), 0, stream>>>(wimg2, wimg, sqp, crp, W2);
  tables_reduce_kernel<<<dim3(129), dim3(128), 0, stream>>>(sqp, crp, sq2, cross);
  w2tail_kernel<<<dim3(512), dim3(128), 0, stream>>>(wimg, W2);
  encdec_kernel<<<dim3(1024), dim3(256), 0, stream>>>(img, wimg, wrec, wrec2, wrecT, wrec2T, W2,
      c1norm, w3norm, w6norm, sq2, cross, Rm);
  gemm_kernel<<<dim3(4, 8, SPLITS), dim3(256), 0, stream>>>(Rm, W2, part);
  loss_kernel<<<dim3(1024), dim3(128), 0, stream>>>(img, part, out);
}

// Round 7
// 126.118 us; speedup vs baseline: 1.4489x; 1.0733x over previous
//
#include <hip/hip_runtime.h>

#define B_   1024
#define G_   512
#define K_   128
#define J_   129
#define E2_  128
#define KK_  16512      /* K_*J_ */
#define KKE_ 16640      /* KK_ + K_ (appended wimg columns) */
#define KKP_ 16896      /* padded: SPLITS*KCHUNK */
#define SPLITS 16
#define KCHUNK 1056     /* KKP_/SPLITS */
#define BK_  32
#define KSTEPS 33       /* KCHUNK/BK_ */
#define GS_  8          /* g-splits for table partials */

using short8 = __attribute__((ext_vector_type(8))) short;
using f32x4  = __attribute__((ext_vector_type(4))) float;

__device__ __forceinline__ float bf2f(unsigned short h){
  return __uint_as_float(((unsigned int)h) << 16);
}
__device__ __forceinline__ unsigned short f2bf(float f){
  unsigned int u = __float_as_uint(f);
  u += 0x7fffu + ((u >> 16) & 1u);          // round-to-nearest-even
  return (unsigned short)(u >> 16);
}

// ---- block (512-thread, 8-wave) reductions -------------------------------
__device__ __forceinline__ float blockSum512(float v, float* red, int t){
  #pragma unroll
  for (int off = 32; off > 0; off >>= 1) v += __shfl_down(v, off);
  __syncthreads();
  if ((t & 63) == 0) red[t >> 6] = v;
  __syncthreads();
  float r = ((red[0] + red[1]) + (red[2] + red[3]))
          + ((red[4] + red[5]) + (red[6] + red[7]));
  __syncthreads();
  return r;
}
__device__ __forceinline__ float blockMax512(float v, float* red, int t){
  #pragma unroll
  for (int off = 32; off > 0; off >>= 1) v = fmaxf(v, __shfl_down(v, off));
  __syncthreads();
  if ((t & 63) == 0) red[t >> 6] = v;
  __syncthreads();
  float r = fmaxf(fmaxf(fmaxf(red[0], red[1]), fmaxf(red[2], red[3])),
                  fmaxf(fmaxf(red[4], red[5]), fmaxf(red[6], red[7])));
  __syncthreads();
  return r;
}
__device__ __forceinline__ int blockArgmax512(float v, int i, float* redf, int* redi, int t){
  #pragma unroll
  for (int off = 32; off > 0; off >>= 1){
    float ov = __shfl_down(v, off);
    int   oi = __shfl_down(i, off);
    if (ov > v || (ov == v && oi < i)){ v = ov; i = oi; }
  }
  __syncthreads();
  if ((t & 63) == 0){ redf[t >> 6] = v; redi[t >> 6] = i; }
  __syncthreads();
  float bv = redf[0]; int bi = redi[0];
  #pragma unroll
  for (int wv = 1; wv < 8; wv++){
    float ov = redf[wv]; int oi = redi[wv];
    if (ov > bv || (ov == bv && oi < bi)){ bv = ov; bi = oi; }
  }
  __syncthreads();
  return bi;
}

// ---- norms + transposes (5 blocks x 1024 threads)
__global__ __launch_bounds__(1024) void norms_kernel(
    const float* __restrict__ wimg, const float* __restrict__ wrec,
    const float* __restrict__ wrec2, float* __restrict__ c1norm,
    float* __restrict__ w3norm, float* __restrict__ w6norm,
    float* __restrict__ wrecT, float* __restrict__ wrec2T){
  int t = threadIdx.x;
  if (blockIdx.x == 0){
    __shared__ float red[8][128];
    int k = t & 127, sl = t >> 7;
    float s = 0.f;
    int g0 = sl * (G_/8);
    for (int g = g0; g < g0 + G_/8; g++){
      float v = wimg[g*K_ + k]; s += v*v;
    }
    red[sl][k] = s;
    __syncthreads();
    if (t < 128){
      float r = 0.f;
      #pragma unroll
      for (int i = 0; i < 8; i++) r += red[i][t];
      c1norm[t] = r;
    }
  } else if (blockIdx.x == 1){
    int wave = t >> 6, lane = t & 63;
    for (int k = wave; k < K_; k += 16){
      float v0 = wrec[k*E2_ + lane], v1 = wrec[k*E2_ + 64 + lane];
      float s = v0*v0 + v1*v1;
      #pragma unroll
      for (int off = 32; off > 0; off >>= 1) s += __shfl_down(s, off);
      if (lane == 0) w3norm[k] = s;
    }
  } else if (blockIdx.x == 2){
    int wave = t >> 6, lane = t & 63;
    for (int j = wave; j < J_; j += 16){
      float v0 = wrec2[j*E2_ + lane], v1 = wrec2[j*E2_ + 64 + lane];
      float s = v0*v0 + v1*v1;
      #pragma unroll
      for (int off = 32; off > 0; off >>= 1) s += __shfl_down(s, off);
      if (lane == 0) w6norm[j] = s;
    }
  } else if (blockIdx.x == 3){
    for (int n = t; n < K_*E2_; n += 1024){
      int k = n >> 7, e = n & 127;
      wrecT[e*K_ + k] = wrec[n];
    }
  } else {
    for (int n = t; n < J_*E2_; n += 1024){
      int j = n >> 7, e = n & 127;
      wrec2T[e*J_ + j] = wrec2[n];
    }
  }
}

// ---- tables partials over g (+ fused W2 bf16 store): n = k*129+j
__global__ __launch_bounds__(128) void tables_part_kernel(
    const float* __restrict__ wimg2, const float* __restrict__ wimg,
    float* __restrict__ sqp, float* __restrict__ crp,
    unsigned short* __restrict__ W2){
  int n  = blockIdx.x * 128 + threadIdx.x;   // [0,16512)
  int gs = blockIdx.y;
  int k = n / J_;
  float s0=0,s1=0,s2=0,s3=0, c0=0,c1=0,c2=0,c3=0;
  int gbase = gs * (G_/GS_);
  #pragma unroll 2
  for (int g = gbase; g < gbase + G_/GS_; g += 4){
    float w0 = wimg2[(size_t)(g  )*KK_ + n];
    float w1 = wimg2[(size_t)(g+1)*KK_ + n];
    float w2 = wimg2[(size_t)(g+2)*KK_ + n];
    float w3 = wimg2[(size_t)(g+3)*KK_ + n];
    W2[(size_t)(g  )*KKP_ + n] = f2bf(w0);
    W2[(size_t)(g+1)*KKP_ + n] = f2bf(w1);
    W2[(size_t)(g+2)*KKP_ + n] = f2bf(w2);
    W2[(size_t)(g+3)*KKP_ + n] = f2bf(w3);
    s0 += w0*w0; s1 += w1*w1; s2 += w2*w2; s3 += w3*w3;
    c0 += wimg[(g  )*K_ + k]*w0;
    c1 += wimg[(g+1)*K_ + k]*w1;
    c2 += wimg[(g+2)*K_ + k]*w2;
    c3 += wimg[(g+3)*K_ + k]*w3;
  }
  sqp[(size_t)gs*KK_ + n] = (s0+s1)+(s2+s3);
  crp[(size_t)gs*KK_ + n] = (c0+c1)+(c2+c3);
}
__global__ __launch_bounds__(128) void tables_reduce_kernel(
    const float* __restrict__ sqp, const float* __restrict__ crp,
    float* __restrict__ sq2, float* __restrict__ cross){
  int n = blockIdx.x * 128 + threadIdx.x;
  float s = 0.f, c = 0.f;
  #pragma unroll
  for (int gs = 0; gs < GS_; gs++){
    s += sqp[(size_t)gs*KK_ + n];
    c += crp[(size_t)gs*KK_ + n];
  }
  sq2[n] = s; cross[n] = c;
}

// ---- W2 tail columns: [KK_,KKE_) = wimg, [KKE_,KKP_) = 0
__global__ __launch_bounds__(128) void w2tail_kernel(
    const float* __restrict__ wimg, unsigned short* __restrict__ W2){
  int g = blockIdx.x, t = threadIdx.x;
  unsigned short* dst = W2 + (size_t)g * KKP_;
  dst[KK_ + t]        = f2bf(wimg[g*K_ + t]);
  dst[KKE_ + t]       = 0;
  dst[KKE_ + 128 + t] = 0;
}

// ---- encode+decode probabilities per b (512 thr, 8 waves); writes R row (bf16)
__global__ __launch_bounds__(512, 8) void encdec_kernel(
    const float* __restrict__ img,  const float* __restrict__ wimg,
    const float* __restrict__ wrec, const float* __restrict__ wrec2,
    const float* __restrict__ wrecT, const float* __restrict__ wrec2T,
    const unsigned short* __restrict__ W2,
    const float* __restrict__ c1norm, const float* __restrict__ w3norm,
    const float* __restrict__ w6norm, const float* __restrict__ sq2,
    const float* __restrict__ cross, unsigned short* __restrict__ Rm){
  __shared__ float simg[G_];
  __shared__ float sp[K_];                 // p (xp_d)
  __shared__ float sqv[J_];                // xp2, then q (xp2_d)
  __shared__ float slat[E2_];
  __shared__ float sd1[K_];
  __shared__ float sh4[4][K_];             // quarter-partials
  __shared__ float xtra[2];                // j=128 extras
  __shared__ float redf[8];
  __shared__ int   redi[8];

  int t = threadIdx.x;
  int b = blockIdx.x;
  int tt = t & 127, q = t >> 7;

  // -- stage 1: xp1 = softmax_k( -(||img-c_k||^2)/512 )
  simg[t] = img[b*G_ + t];
  __syncthreads();
  float a0 = simg[t];
  float imgnorm = blockSum512(a0*a0, redf, t);

  {
    // d1[k=tt]: lanes tt consecutive -> coalesced column loads; g quarter-split
    float d0=0,d1v=0,d2=0,d3v=0;
    int g0 = q * 128;
    const float* wcol = wimg + tt;
    for (int g = g0; g < g0 + 128; g += 4){
      d0  += simg[g  ] * wcol[(g  )*K_];
      d1v += simg[g+1] * wcol[(g+1)*K_];
      d2  += simg[g+2] * wcol[(g+2)*K_];
      d3v += simg[g+3] * wcol[(g+3)*K_];
    }
    sh4[q][tt] = (d0+d1v)+(d2+d3v);
  }
  __syncthreads();
  float d1 = (sh4[0][tt] + sh4[1][tt]) + (sh4[2][tt] + sh4[3][tt]);
  if (q == 0) sd1[tt] = d1;
  float xh1 = -(imgnorm - 2.f*d1 + c1norm[tt]) * (1.f/512.f);
  float m1 = blockMax512(xh1, redf, t);
  float ex1 = expf(xh1 - m1);
  float s1 = blockSum512((q == 0) ? ex1 : 0.f, redf, t);
  if (q == 0) sp[tt] = ex1 / s1;
  __syncthreads();

  // -- stage 2: lat[e=tt] = sum_k xp1[k]*wrec[k][e], k quarter-split (coalesced)
  {
    float l0=0,l1=0;
    int k0 = q * 32;
    for (int k = k0; k < k0 + 32; k += 2){
      l0 += sp[k  ] * wrec[(k  )*E2_ + tt];
      l1 += sp[k+1] * wrec[(k+1)*E2_ + tt];
    }
    sh4[q][tt] = l0 + l1;
  }
  __syncthreads();
  float lat = (sh4[0][tt] + sh4[1][tt]) + (sh4[2][tt] + sh4[3][tt]);
  if (q == 0) slat[tt] = lat;
  float latnorm = blockSum512((q == 0) ? lat*lat : 0.f, redf, t);

  // -- stage 3: d3[k=tt] = sum_e lat[e]*wrecT[e][k], e quarter-split (coalesced)
  {
    float l0=0,l1=0;
    int e0 = q * 32;
    const float* rT = wrecT + tt;
    for (int e = e0; e < e0 + 32; e += 2){
      l0 += slat[e  ] * rT[(e  )*K_];
      l1 += slat[e+1] * rT[(e+1)*K_];
    }
    sh4[q][tt] = l0 + l1;
  }
  __syncthreads();
  float d3 = (sh4[0][tt] + sh4[1][tt]) + (sh4[2][tt] + sh4[3][tt]);
  float xh3 = -(latnorm - 2.f*d3 + w3norm[tt]) * (1.f/128.f);
  float m3 = blockMax512(xh3, redf, t);
  float ex3 = expf(xh3 - m3);
  float s3 = blockSum512((q == 0) ? ex3 : 0.f, redf, t);
  if (q == 0) sp[tt] = ex3 / s3;          // final p (xp_d)
  int idxb = blockArgmax512(xh3, tt, redf, redi, t);
  float dsq = imgnorm - 2.f*sd1[idxb] + c1norm[idxb];

  // -- stage 5: di[j=tt] = sum_g simg[g]*W2[g][idxb*J+j]; g quarter-split; j=128 via wave0
  {
    const unsigned short* Wb = W2 + (size_t)idxb * J_ + tt;
    float s0=0,s1=0,s2=0,s3=0;
    int g0 = q * 128;
    for (int g = g0; g < g0 + 128; g += 4){
      s0 += simg[g  ] * bf2f(Wb[(size_t)(g  )*KKP_]);
      s1 += simg[g+1] * bf2f(Wb[(size_t)(g+1)*KKP_]);
      s2 += simg[g+2] * bf2f(Wb[(size_t)(g+2)*KKP_]);
      s3 += simg[g+3] * bf2f(Wb[(size_t)(g+3)*KKP_]);
    }
    sh4[q][tt] = (s0+s1)+(s2+s3);
  }
  if (t < 64){
    const unsigned short* Wb8 = W2 + (size_t)idxb * J_ + 128;
    float s = 0.f;
    #pragma unroll
    for (int m = 0; m < 8; m++){
      int g = t + 64*m;
      s += simg[g] * bf2f(Wb8[(size_t)g * KKP_]);
    }
    #pragma unroll
    for (int off = 32; off > 0; off >>= 1) s += __shfl_down(s, off);
    if (t == 0) xtra[0] = s;
  }
  __syncthreads();
  float xh2 = -3e38f;
  if (t < J_){
    float di = (t < 128) ? ((sh4[0][t] + sh4[1][t]) + (sh4[2][t] + sh4[3][t])) : xtra[0];
    int nb = idxb*J_ + t;
    xh2 = -(dsq - 2.f*(di - cross[nb]) + sq2[nb]) * (1.f/512.f);
  }
  float m2 = blockMax512(xh2, redf, t);
  float ea = (t < J_) ? expf(xh2 - m2) : 0.f;
  float s2 = blockSum512(ea, redf, t);
  if (t < J_) sqv[t] = ea / s2;
  __syncthreads();

  // -- stage 6: lat2[e=tt] = sum_j xp2[j]*wrec2[j][e], j quarter-split 33/32/32/32
  {
    float l = 0.f;
    int j0 = (q == 0) ? 0 : (q*32 + 1);
    int j1 = q*32 + 33;
    for (int j = j0; j < j1; j++)
      l += sqv[j] * wrec2[j*E2_ + tt];
    sh4[q][tt] = l;
  }
  __syncthreads();
  float lat2 = (sh4[0][tt] + sh4[1][tt]) + (sh4[2][tt] + sh4[3][tt]);
  if (q == 0) slat[tt] = lat2;
  float l2n = blockSum512((q == 0) ? lat2*lat2 : 0.f, redf, t);

  // -- stage 7: d6[j=tt] = sum_e lat2[e]*wrec2T[e][j], e quarter-split; j=128 via wave0
  {
    float l0=0,l1=0;
    int e0 = q * 32;
    const float* rT = wrec2T + tt;
    for (int e = e0; e < e0 + 32; e += 2){
      l0 += slat[e  ] * rT[(e  )*J_];
      l1 += slat[e+1] * rT[(e+1)*J_];
    }
    sh4[q][tt] = l0 + l1;
  }
  if (t < 64){
    float s = slat[t]*wrec2T[t*J_ + 128] + slat[t+64]*wrec2T[(t+64)*J_ + 128];
    #pragma unroll
    for (int off = 32; off > 0; off >>= 1) s += __shfl_down(s, off);
    if (t == 0) xtra[1] = s;
  }
  __syncthreads();
  float xh6 = -3e38f;
  if (t < J_){
    float d6 = (t < 128) ? ((sh4[0][t] + sh4[1][t]) + (sh4[2][t] + sh4[3][t])) : xtra[1];
    xh6 = -(l2n - 2.f*d6 + w6norm[t]) * (1.f/128.f);
  }
  float m6 = blockMax512(xh6, redf, t);
  float e6 = (t < J_) ? expf(xh6 - m6) : 0.f;
  float s6 = blockSum512(e6, redf, t);
  if (t < J_) sqv[t] = e6 / s6;
  __syncthreads();

  // -- R fill: [0,KK_): p_k*q_j ; [KK_,KKE_): p ; rest 0  (incremental k,j; stride 512)
  unsigned short* Rrow = Rm + (size_t)b * KKP_;
  int k = (t >= 387) ? 3 : (t >= 258) ? 2 : (t >= 129) ? 1 : 0;
  int j = t - k*J_;
  for (int kk = t; kk < KKP_; kk += 512){
    float v = 0.f;
    if (kk < KK_)        v = sp[k] * sqv[j];
    else if (kk < KKE_)  v = sp[kk - KK_];
    Rrow[kk] = f2bf(v);
    if (j < 4){ j += 125; k += 3; } else { j -= 4; k += 4; }
  }
}

// ---- big einsum as bf16 NT GEMM with split-K:
// part[z][b][g] = sum_{kk in chunk z} R[b,kk]*W2[g,kk]
__global__ __launch_bounds__(256) void gemm_kernel(
    const unsigned short* __restrict__ Rm, const unsigned short* __restrict__ W2,
    float* __restrict__ part){
  __shared__ __align__(16) unsigned int lds[2*128*20];   // 80B-stride rows, A then B
  unsigned int* lA = lds;
  unsigned int* lB = lds + 128*20;
  int tid = threadIdx.x;
  int l = tid & 63;
  int w = tid >> 6;
  int wr = (w >> 1) * 64, wc = (w & 1) * 64;
  int b0 = blockIdx.y * 128, g0 = blockIdx.x * 128;
  size_t kkbase = (size_t)blockIdx.z * KCHUNK;

  int srow = tid >> 2, scol = tid & 3;
  const unsigned short* pa = Rm + (size_t)(b0 + srow)*KKP_ + kkbase + scol*8;
  const unsigned short* pb = W2 + (size_t)(g0 + srow)*KKP_ + kkbase + scol*8;
  const size_t half = (size_t)64 * KKP_;
  unsigned int woff = srow*20 + scol*4;

  int lrow = l & 15, lko = (l >> 4) << 2;

  f32x4 zero4 = {0.f, 0.f, 0.f, 0.f};
  f32x4 acc[4][4];
  #pragma unroll
  for (int mi = 0; mi < 4; mi++)
    #pragma unroll
    for (int ni = 0; ni < 4; ni++) acc[mi][ni] = zero4;

  for (int s = 0; s < KSTEPS; s++){
    uint4 va0 = *(const uint4*)pa;
    uint4 va1 = *(const uint4*)(pa + half);
    uint4 vb0 = *(const uint4*)pb;
    uint4 vb1 = *(const uint4*)(pb + half);
    pa += BK_; pb += BK_;
    __syncthreads();
    *(uint4*)(lA + woff)          = va0;
    *(uint4*)(lA + woff + 64*20)  = va1;
    *(uint4*)(lB + woff)          = vb0;
    *(uint4*)(lB + woff + 64*20)  = vb1;
    __syncthreads();
    short8 af[4], bfv[4];
    #pragma unroll
    for (int mi = 0; mi < 4; mi++)
      af[mi] = *(const short8*)(lA + (wr + mi*16 + lrow)*20 + lko);
    #pragma unroll
    for (int ni = 0; ni < 4; ni++)
      bfv[ni] = *(const short8*)(lB + (wc + ni*16 + lrow)*20 + lko);
    #pragma unroll
    for (int mi = 0; mi < 4; mi++)
      #pragma unroll
      for (int ni = 0; ni < 4; ni++)
        acc[mi][ni] = __builtin_amdgcn_mfma_f32_16x16x32_bf16(af[mi], bfv[ni], acc[mi][ni], 0, 0, 0);
  }

  float* P = part + ((size_t)blockIdx.z * B_ + b0) * G_ + g0;
  int rh = (l >> 4) << 2, cl = l & 15;
  #pragma unroll
  for (int mi = 0; mi < 4; mi++)
    #pragma unroll
    for (int ni = 0; ni < 4; ni++)
      #pragma unroll
      for (int r = 0; r < 4; r++){
        int row = wr + mi*16 + rh + r;
        int col = wc + ni*16 + cl;
        P[(size_t)row*G_ + col] = acc[mi][ni][r];
      }
}

// ---- loss[b] = mean_g ( (sum_z part[z][b][g]) - img[b][g] )^2
__global__ __launch_bounds__(128) void loss_kernel(
    const float* __restrict__ img, const float* __restrict__ part,
    float* __restrict__ out){
  __shared__ float redf[2];
  int t = threadIdx.x, b = blockIdx.x;
  float acc = 0.f;
  for (int g = t; g < G_; g += 128){
    float x = 0.f;
    #pragma unroll
    for (int z = 0; z < SPLITS; z++)
      x += part[((size_t)z*B_ + b)*G_ + g];
    float d = x - img[b*G_ + g];
    acc += d*d;
  }
  #pragma unroll
  for (int off = 32; off > 0; off >>= 1) acc += __shfl_down(acc, off);
  __syncthreads();
  if ((t & 63) == 0) redf[t >> 6] = acc;
  __syncthreads();
  if (t == 0) out[b] = (redf[0] + redf[1]) * (1.f/512.f);
}

extern "C" void kernel_launch(void* const* d_in, const int* in_sizes, int n_in,
                              void* d_out, int out_size, void* d_ws, size_t ws_size,
                              hipStream_t stream){
  (void)in_sizes; (void)n_in; (void)out_size; (void)ws_size;
  const float* img   = (const float*)d_in[0];
  const float* wimg  = (const float*)d_in[1];
  const float* wrec  = (const float*)d_in[2];
  const float* wrec2 = (const float*)d_in[3];
  const float* wimg2 = (const float*)d_in[4];
  float* out = (float*)d_out;

  char* ws = (char*)d_ws;
  size_t off = 0;
  auto alloc = [&](size_t bytes) -> void* {
    void* p = ws + off;
    off += (bytes + 255) & ~(size_t)255;
    return p;
  };
  unsigned short* W2   = (unsigned short*)alloc((size_t)G_ * KKP_ * 2);
  unsigned short* Rm   = (unsigned short*)alloc((size_t)B_ * KKP_ * 2);
  float* part   = (float*)alloc((size_t)SPLITS * B_ * G_ * 4);
  float* sqp    = (float*)alloc((size_t)GS_ * KK_ * 4);
  float* crp    = (float*)alloc((size_t)GS_ * KK_ * 4);
  float* sq2    = (float*)alloc((size_t)KK_ * 4);
  float* cross  = (float*)alloc((size_t)KK_ * 4);
  float* c1norm = (float*)alloc(K_ * 4);
  float* w3norm = (float*)alloc(K_ * 4);
  float* w6norm = (float*)alloc(J_ * 4);
  float* wrecT  = (float*)alloc((size_t)K_ * E2_ * 4);
  float* wrec2T = (float*)alloc((size_t)J_ * E2_ * 4);

  norms_kernel<<<dim3(5), dim3(1024), 0, stream>>>(wimg, wrec, wrec2, c1norm, w3norm, w6norm, wrecT, wrec2T);
  tables_part_kernel<<<dim3(129, GS_), dim3(128), 0, stream>>>(wimg2, wimg, sqp, crp, W2);
  tables_reduce_kernel<<<dim3(129), dim3(128), 0, stream>>>(sqp, crp, sq2, cross);
  w2tail_kernel<<<dim3(512), dim3(128), 0, stream>>>(wimg, W2);
  encdec_kernel<<<dim3(1024), dim3(512), 0, stream>>>(img, wimg, wrec, wrec2, wrecT, wrec2T, W2,
      c1norm, w3norm, w6norm, sq2, cross, Rm);
  gemm_kernel<<<dim3(4, 8, SPLITS), dim3(256), 0, stream>>>(Rm, W2, part);
  loss_kernel<<<dim3(1024), dim3(128), 0, stream>>>(img, part, out);
}